// Round 10
// baseline (144.576 us; speedup 1.0000x reference)
//
#include <hip/hip_runtime.h>
#include <stdint.h>

#define NQ 10
#define NL 4

typedef unsigned int u32;
typedef _Float16 f16x8 __attribute__((ext_vector_type(8)));
typedef float f32x16 __attribute__((ext_vector_type(16)));
typedef u32 u32x4 __attribute__((ext_vector_type(4)));

// CNOT-ring permutation F (XOR-linear): F = X ∘ (A⊗B) in gather convention
// (S_next[i] = U[F(i)]), where A = B = Gray map g(k) = (k^(k>>1))&31 (folded
// into prep via lane-index permutation of layers 0..2's W,V), and runtime
// X: row ^= c0*16, col ^= r0*31 (in-register; verified vs R9 RT2 at elements
// (k0,c1)->U[24,1], (k5,c2)->U[7,19], odd-row case (r17,c30)).
// F^-1 sign masks (epilogue): bit_{9-q}(F^-1(r,c)) = par(r&Mrow_q)^par(c&Mcol_q)
// Mrow: q0=0x0F q1=0x18 q2=0x1C q3=0x1E q>=4=0x1F

// ---------- helpers ----------
__device__ __forceinline__ f32x16 mfma16(f16x8 a, f16x8 b, f32x16 c) {
    return __builtin_amdgcn_mfma_f32_32x32x16_f16(a, b, c, 0, 0, 0);
}
__device__ __forceinline__ f32x16 zero16() {
    f32x16 z;
#pragma unroll
    for (int i = 0; i < 16; i++) z[i] = 0.f;
    return z;
}
__device__ __forceinline__ f16x8 negf(f16x8 v) {
    u32x4 u = __builtin_bit_cast(u32x4, v);
#pragma unroll
    for (int i = 0; i < 4; i++) u[i] ^= 0x80008000u;
    return __builtin_bit_cast(f16x8, u);
}
__device__ __forceinline__ u32 pk2(float a, float b) {
    auto h = __builtin_amdgcn_cvt_pkrtz(a, b);
    return __builtin_bit_cast(u32, h);
}
__device__ __forceinline__ u32 permlo(u32 a, u32 b) { return __builtin_amdgcn_perm(b, a, 0x05040100u); }
__device__ __forceinline__ u32 permhi(u32 a, u32 b) { return __builtin_amdgcn_perm(b, a, 0x07060302u); }
__device__ __forceinline__ f16x8 mk8(u32 a, u32 b, u32 c, u32 d) {
    u32x4 v; v[0] = a; v[1] = b; v[2] = c; v[3] = d;
    return __builtin_bit_cast(f16x8, v);
}
template <int MASK>
__device__ __forceinline__ float swz(float v) {
    return __int_as_float(__builtin_amdgcn_ds_swizzle(__float_as_int(v), (MASK << 10) | 0x1F));
}
template <int MASK>
__device__ __forceinline__ u32 swzu(u32 v) {
    return (u32)__builtin_amdgcn_ds_swizzle((int)v, (MASK << 10) | 0x1F);
}
__device__ __forceinline__ u32 bpermu(int addr, u32 v) {
    return (u32)__builtin_amdgcn_ds_bpermute(addr, (int)v);
}
__device__ __forceinline__ float rdlane(float v, int l) {
    return __uint_as_float((u32)__builtin_amdgcn_readlane((int)__float_as_uint(v), l));
}
__device__ __forceinline__ void cmulh(float ar, float ai, float br, float bi, float& cr, float& ci) {
    cr = ar * br - ai * bi;
    ci = ar * bi + ai * br;
}

// C-layout f32x16 -> A/B-frag pair (f16) via in-register half-exchange (R6/R9-validated).
__device__ __forceinline__ void c2a(const f32x16& V, bool hb, int addr32, u32 (&o)[8]) {
    u32 pw[8];
#pragma unroll
    for (int p = 0; p < 8; p++) pw[p] = pk2(V[2 * p], V[2 * p + 1]);
    u32 s0 = hb ? pw[0] : pw[2];
    u32 s1 = hb ? pw[1] : pw[3];
    u32 s2 = hb ? pw[4] : pw[6];
    u32 s3 = hb ? pw[5] : pw[7];
    u32 r0 = bpermu(addr32, s0), r1 = bpermu(addr32, s1);
    u32 r2 = bpermu(addr32, s2), r3 = bpermu(addr32, s3);
    o[0] = hb ? r0 : pw[0]; o[1] = hb ? r1 : pw[1];
    o[2] = hb ? pw[2] : r0; o[3] = hb ? pw[3] : r1;
    o[4] = hb ? r2 : pw[4]; o[5] = hb ? r3 : pw[5];
    o[6] = hb ? pw[6] : r2; o[7] = hb ? pw[7] : r3;
}

// ---------- prep: fused gates -> W,V frags (+ Srow signs) in d_ws ----------
// frag f = l*8 + mat*4 + part*2 + kh; element frag[(f*64+lane)*8+j]; f=32,33: Srow.
// Layers 0..2: lane (output) index Gray-permuted = folded (A⊗B) of the CNOT perm.
// Launch <<<2,1024>>> (2048-thread index space).
__global__ void tq_prep(const float* __restrict__ theta, uint16_t* __restrict__ frag) {
    __shared__ float g[NL * NQ][8];
    int tt = threadIdx.x;
    if (tt < NL * NQ) {
        float hx = 0.5f * theta[tt * 3 + 0];
        float hy = 0.5f * theta[tt * 3 + 1];
        float hz = 0.5f * theta[tt * 3 + 2];
        float cx = cosf(hx), sx = sinf(hx);
        float cy = cosf(hy), sy = sinf(hy);
        float cz = cosf(hz), sz = sinf(hz);
        float m00r = cx * cy, m00i = -sx * sy;
        float m01r = -cx * sy, m01i = -sx * cy;
        float m10r = cx * sy, m10i = -sx * cy;
        float m11r = cx * cy, m11i = sx * sy;
        float g00r, g00i, g01r, g01i, g10r, g10i, g11r, g11i;
        cmulh(m00r, m00i, cz, -sz, g00r, g00i);
        cmulh(m10r, m10i, cz, -sz, g10r, g10i);
        cmulh(m01r, m01i, cz, sz, g01r, g01i);
        cmulh(m11r, m11i, cz, sz, g11r, g11i);
        g[tt][0] = g00r; g[tt][1] = g00i; g[tt][2] = g01r; g[tt][3] = g01i;
        g[tt][4] = g10r; g[tt][5] = g10i; g[tt][6] = g11r; g[tt][7] = g11i;
    }
    __syncthreads();
    int t = blockIdx.x * blockDim.x + tt;  // 0..2047
    int lane = t & 63, kh = (t >> 6) & 1, part = (t >> 7) & 1, mat = (t >> 8) & 1, l = t >> 9;
    int mn = lane & 31, hf = (lane >> 5) & 1;
    int mne = (l < NL - 1) ? ((mn ^ (mn >> 1)) & 31) : mn;  // Gray fold for layers 0..2
#pragma unroll
    for (int j = 0; j < 8; j++) {
        int k = kh * 16 + hf * 8 + j;
        float pr = 1.f, pi = 0.f;
#pragma unroll
        for (int u = 0; u < 5; u++) {
            int q = mat ? (5 + u) : u;
            int bi_ = (k >> (4 - u)) & 1;
            int bo_ = (mne >> (4 - u)) & 1;
            const float* gg = g[l * NQ + q];
            float er = gg[(bi_ * 2 + bo_) * 2 + 0];
            float ei = gg[(bi_ * 2 + bo_) * 2 + 1];
            float nr, ni;
            cmulh(pr, pi, er, ei, nr, ni);
            pr = nr;
            pi = ni;
        }
        float v = part ? pi : pr;
        _Float16 h = (_Float16)v;
        frag[t * 8 + j] = __builtin_bit_cast(unsigned short, h);
    }
    // Srow sign frags (f=32,33): A[m][k] = (-1)^par(k & Mrow(m)), m = lane&31
    if (blockIdx.x == 0 && tt < 128) {
        int ln = tt & 63, kh2 = tt >> 6;
        int q = ln & 31, hf2 = (ln >> 5) & 1;
        u32 M = (q == 0) ? 0xFu : (q == 1) ? 0x18u : (q == 2) ? 0x1Cu : (q == 3) ? 0x1Eu : 0x1Fu;
        uint16_t* o = frag + ((32 + kh2) * 64 + ln) * 8;
#pragma unroll
        for (int j = 0; j < 8; j++) {
            int k = kh2 * 16 + hf2 * 8 + j;
            float v = (__builtin_popcount((u32)k & M) & 1) ? -1.f : 1.f;
            _Float16 h = (_Float16)v;
            o[j] = __builtin_bit_cast(unsigned short, h);
        }
    }
}

// ---------- main: one wave per sample; zero LDS allocation ----------
__global__ __launch_bounds__(256) void tq_main(
    const float* __restrict__ x, const float* __restrict__ encW,
    const float* __restrict__ encb, const uint16_t* __restrict__ frag,
    float* __restrict__ out, int batch) {
    int tid = threadIdx.x;
    int wave = (blockIdx.x * blockDim.x + tid) >> 6;
    int lane = tid & 63;
    if (wave >= batch) return;
    const int col = lane & 31;
    const int half_ = lane >> 5;
    const bool hb = half_ != 0;
    const bool c0 = (lane & 1) != 0;
    const int addr32 = (lane ^ 32) << 2;

    // ---- encoding: RY(enc) product state, built directly as A-frag ----
    float x0 = x[wave * 3 + 0], x1 = x[wave * 3 + 1], x2 = x[wave * 3 + 2];
    float hc = 1.f, hs = 0.f;
    if (lane < NQ) {
        float tta = 3.14159265358979323846f *
                    tanhf(x0 * encW[lane * 3 + 0] + x1 * encW[lane * 3 + 1] +
                          x2 * encW[lane * 3 + 2] + encb[lane]);
        float h = 0.5f * tta;
        hc = cosf(h);
        hs = sinf(h);
    }
    float fcv[NQ], fsv[NQ];
#pragma unroll
    for (int q = 0; q < NQ; q++) {
        fcv[q] = rdlane(hc, q);  // wave-uniform -> SGPR, no DS traffic
        fsv[q] = rdlane(hs, q);
    }
    float colf = 1.f;
    colf *= ((col >> 4) & 1) ? -fsv[5] : fcv[5];
    colf *= ((col >> 3) & 1) ? -fsv[6] : fcv[6];
    colf *= ((col >> 2) & 1) ? -fsv[7] : fcv[7];
    colf *= ((col >> 1) & 1) ? -fsv[8] : fcv[8];
    colf *= (col & 1) ? -fsv[9] : fcv[9];
    float f1h = half_ ? -fsv[1] : fcv[1];
    float gj[8];
#pragma unroll
    for (int j = 0; j < 8; j++) {
        gj[j] = ((j & 4) ? -fsv[2] : fcv[2]) * ((j & 2) ? -fsv[3] : fcv[3]) *
                ((j & 1) ? -fsv[4] : fcv[4]);
    }
    f16x8 Sr0, Sr1, Si0, Si1;
#pragma unroll
    for (int j = 0; j < 8; j++) {
        Sr0[j] = (_Float16)(fcv[0] * f1h * gj[j] * colf);
        Sr1[j] = (_Float16)(-fsv[0] * f1h * gj[j] * colf);
        Si0[j] = (_Float16)0.f;
        Si1[j] = (_Float16)0.f;
    }

    const f16x8* fr = (const f16x8*)frag;
#define FRAG(f) fr[((f)*64) + lane]

    f32x16 Ur, Ui;
#pragma unroll
    for (int l = 0; l < NL; l++) {
        f16x8 Wr0 = FRAG(8 * l + 0), Wr1 = FRAG(8 * l + 1);
        f16x8 Wi0 = FRAG(8 * l + 2), Wi1 = FRAG(8 * l + 3);
        f16x8 Vr0 = FRAG(8 * l + 4), Vr1 = FRAG(8 * l + 5);
        f16x8 Vi0 = FRAG(8 * l + 6), Vi1 = FRAG(8 * l + 7);

        // GEMM1': T' = S^T * W^T = T^T (S-frag as A; W-frag as B)
        f32x16 Tr = zero16(), Ti = zero16();
        Tr = mfma16(Sr0, Wr0, Tr);
        Tr = mfma16(Sr1, Wr1, Tr);
        Ti = mfma16(Sr0, Wi0, Ti);
        Ti = mfma16(Sr1, Wi1, Ti);
        if (l > 0) {
            f16x8 nSi0 = negf(Si0), nSi1 = negf(Si1);
            Tr = mfma16(nSi0, Wi0, Tr);
            Tr = mfma16(nSi1, Wi1, Tr);
            Ti = mfma16(Si0, Wr0, Ti);
            Ti = mfma16(Si1, Wr1, Ti);
        }

        // C(T') -> A-frag(T): register half-exchange, no LDS
        u32 oR[8], oI[8];
        c2a(Tr, hb, addr32, oR);
        c2a(Ti, hb, addr32, oI);
        f16x8 TAr0 = mk8(oR[0], oR[1], oR[2], oR[3]);
        f16x8 TAr1 = mk8(oR[4], oR[5], oR[6], oR[7]);
        f16x8 TAi0 = mk8(oI[0], oI[1], oI[2], oI[3]);
        f16x8 TAi1 = mk8(oI[4], oI[5], oI[6], oI[7]);

        // GEMM2: U = T * V
        Ur = zero16();
        Ui = zero16();
        Ur = mfma16(TAr0, Vr0, Ur);
        Ur = mfma16(TAr1, Vr1, Ur);
        {
            f16x8 nTAi0 = negf(TAi0), nTAi1 = negf(TAi1);
            Ur = mfma16(nTAi0, Vi0, Ur);
            Ur = mfma16(nTAi1, Vi1, Ur);
        }
        Ui = mfma16(TAr0, Vi0, Ui);
        Ui = mfma16(TAr1, Vi1, Ui);
        Ui = mfma16(TAi0, Vr0, Ui);
        Ui = mfma16(TAi1, Vr1, Ui);

        if (l < NL - 1) {
            // X-step (residual CNOT perm; (A⊗B) part folded into prep):
            // new[R,C] = U''[R ^ C0*16, C ^ R0*31]; word gi <-> row (gi&3)+8*(gi>>2)+4*half
            u32 w_[16];
#pragma unroll
            for (int gi = 0; gi < 16; gi++) w_[gi] = pk2(Ur[gi], Ui[gi]);
            u32 sw_[16];
#pragma unroll
            for (int gi = 1; gi < 16; gi += 2) sw_[gi] = swzu<0x1F>(w_[gi]);
            u32 xw[16];
#pragma unroll
            for (int gi = 0; gi < 16; gi += 2) xw[gi] = c0 ? w_[gi ^ 8] : w_[gi];
#pragma unroll
            for (int gi = 1; gi < 16; gi += 2) xw[gi] = c0 ? sw_[gi ^ 8] : sw_[gi];
            // half-exchange: h0 sends rows {8..11,24..27}, receives {4..7,20..23}
            u32 r_[8];
#pragma unroll
            for (int j = 0; j < 4; j++) {
                u32 s_ = hb ? xw[j] : xw[4 + j];
                r_[j] = bpermu(addr32, s_);
            }
#pragma unroll
            for (int j = 0; j < 4; j++) {
                u32 s_ = hb ? xw[8 + j] : xw[12 + j];
                r_[4 + j] = bpermu(addr32, s_);
            }
            // arrange k-ordered rows (k = kh*16 + half*8 + t)
            u32 k0[8], k1[8];
#pragma unroll
            for (int t = 0; t < 4; t++) {
                k0[t] = hb ? r_[t] : xw[t];
                k0[4 + t] = hb ? xw[4 + t] : r_[t];
                k1[t] = hb ? r_[4 + t] : xw[8 + t];
                k1[4 + t] = hb ? xw[12 + t] : r_[4 + t];
            }
            Sr0 = mk8(permlo(k0[0], k0[1]), permlo(k0[2], k0[3]),
                      permlo(k0[4], k0[5]), permlo(k0[6], k0[7]));
            Sr1 = mk8(permlo(k1[0], k1[1]), permlo(k1[2], k1[3]),
                      permlo(k1[4], k1[5]), permlo(k1[6], k1[7]));
            Si0 = mk8(permhi(k0[0], k0[1]), permhi(k0[2], k0[3]),
                      permhi(k0[4], k0[5]), permhi(k0[6], k0[7]));
            Si1 = mk8(permhi(k1[0], k1[1]), permhi(k1[2], k1[3]),
                      permhi(k1[4], k1[5]), permhi(k1[6], k1[7]));
        }
    }

    // ---- epilogue: D = Srow * P (MFMA), Srow frags from d_ws ----
    f32x16 P;
#pragma unroll
    for (int gi = 0; gi < 16; gi++) P[gi] = Ur[gi] * Ur[gi] + Ui[gi] * Ui[gi];
    u32 po[8];
    c2a(P, hb, addr32, po);
    f16x8 PB0 = mk8(po[0], po[1], po[2], po[3]);
    f16x8 PB1 = mk8(po[4], po[5], po[6], po[7]);
    f16x8 Srw0 = FRAG(32), Srw1 = FRAG(33);
    f32x16 D = mfma16(Srw0, PB0, mfma16(Srw1, PB1, zero16()));

    u32 b4 = (col >> 4) & 1, b3 = (col >> 3) & 1, b2 = (col >> 2) & 1,
        b1 = (col >> 1) & 1, b0 = col & 1;
    u32 p4 = b4, p43 = p4 ^ b3, p432 = p43 ^ b2, p4321 = p432 ^ b1, pall = p4321 ^ b0;
    // slots 0..5: h=0 -> q {0,1,2,3,8,9}; h=1 -> q {4,5,6,7,-,-}
    u32 sg[6];
    sg[0] = hb ? 0u : pall;
    sg[1] = hb ? p4 : 0u;
    sg[2] = hb ? p43 : 0u;
    sg[3] = hb ? p432 : 0u;
    sg[4] = hb ? 0u : p4321;
    sg[5] = hb ? 0u : pall;
    float red[6];
#pragma unroll
    for (int s = 0; s < 6; s++) {
        float v = __uint_as_float(__float_as_uint(D[s]) ^ (sg[s] << 31));
        v += swz<1>(v);
        v += swz<2>(v);
        v += swz<4>(v);
        v += swz<8>(v);
        v += swz<16>(v);
        red[s] = v;
    }
    int cc = col - ((col >= 4) ? 4 : 0);
    float v = red[0];
    v = (cc == 1) ? red[1] : v;
    v = (cc == 2) ? red[2] : v;
    v = (cc == 3) ? red[3] : v;
    v = (cc == 4) ? red[4] : v;
    v = (cc == 5) ? red[5] : v;
    bool st = hb ? (col >= 4 && col < 8) : (col < 4 || col == 8 || col == 9);
    if (st) out[wave * NQ + col] = v;
}

extern "C" void kernel_launch(void* const* d_in, const int* in_sizes, int n_in,
                              void* d_out, int out_size, void* d_ws, size_t ws_size,
                              hipStream_t stream) {
    const float* x = (const float*)d_in[0];
    const float* encW = (const float*)d_in[1];
    const float* encb = (const float*)d_in[2];
    const float* th = (const float*)d_in[3];
    float* out = (float*)d_out;
    uint16_t* frag = (uint16_t*)d_ws;  // 34 frags * 64 lanes * 8 f16 (~35 KB)
    int batch = in_sizes[0] / 3;

    tq_prep<<<2, 1024, 0, stream>>>(th, frag);
    int total_threads = batch * 64;
    tq_main<<<(total_threads + 255) / 256, 256, 0, stream>>>(x, encW, encb, frag, out, batch);
}

// Round 11
// 102.203 us; speedup vs baseline: 1.4146x; 1.4146x over previous
//
#include <hip/hip_runtime.h>
#include <stdint.h>

#define NQ 10
#define NL 4

typedef unsigned int u32;
typedef _Float16 f16x8 __attribute__((ext_vector_type(8)));
typedef float f32x16 __attribute__((ext_vector_type(16)));
typedef u32 u32x4 __attribute__((ext_vector_type(4)));

// CNOT-ring permutation F = X ∘ (Gray⊗Gray) in gather convention (R10-validated):
// Gray map folded into prep (lane-index permutation of layers 0..2's W,V);
// runtime X: row ^= c0*16, col ^= r0*31, done fully in registers.
// F^-1 sign masks (epilogue): bit_{9-q}(F^-1(r,c)) = par(r&Mrow_q)^par(c&Mcol_q)
// Mrow: q0=0x0F q1=0x18 q2=0x1C q3=0x1E q>=4=0x1F

// ---------- helpers ----------
__device__ __forceinline__ f32x16 mfma16(f16x8 a, f16x8 b, f32x16 c) {
    return __builtin_amdgcn_mfma_f32_32x32x16_f16(a, b, c, 0, 0, 0);
}
__device__ __forceinline__ f32x16 zero16() {
    f32x16 z;
#pragma unroll
    for (int i = 0; i < 16; i++) z[i] = 0.f;
    return z;
}
__device__ __forceinline__ f16x8 negf(f16x8 v) {
    u32x4 u = __builtin_bit_cast(u32x4, v);
#pragma unroll
    for (int i = 0; i < 4; i++) u[i] ^= 0x80008000u;
    return __builtin_bit_cast(f16x8, u);
}
__device__ __forceinline__ u32 pk2(float a, float b) {
    auto h = __builtin_amdgcn_cvt_pkrtz(a, b);
    return __builtin_bit_cast(u32, h);
}
__device__ __forceinline__ u32 permlo(u32 a, u32 b) { return __builtin_amdgcn_perm(b, a, 0x05040100u); }
__device__ __forceinline__ u32 permhi(u32 a, u32 b) { return __builtin_amdgcn_perm(b, a, 0x07060302u); }
__device__ __forceinline__ f16x8 mk8(u32 a, u32 b, u32 c, u32 d) {
    u32x4 v; v[0] = a; v[1] = b; v[2] = c; v[3] = d;
    return __builtin_bit_cast(f16x8, v);
}
template <int MASK>
__device__ __forceinline__ float swz(float v) {
    return __int_as_float(__builtin_amdgcn_ds_swizzle(__float_as_int(v), (MASK << 10) | 0x1F));
}
template <int MASK>
__device__ __forceinline__ u32 swzu(u32 v) {
    return (u32)__builtin_amdgcn_ds_swizzle((int)v, (MASK << 10) | 0x1F);
}
__device__ __forceinline__ u32 bpermu(int addr, u32 v) {
    return (u32)__builtin_amdgcn_ds_bpermute(addr, (int)v);
}
__device__ __forceinline__ void cmulh(float ar, float ai, float br, float bi, float& cr, float& ci) {
    cr = ar * br - ai * bi;
    ci = ar * bi + ai * br;
}

// C-layout f32x16 -> A/B-frag pair (f16) via in-register half-exchange (R6/R9-validated).
__device__ __forceinline__ void c2a(const f32x16& V, bool hb, int addr32, u32 (&o)[8]) {
    u32 pw[8];
#pragma unroll
    for (int p = 0; p < 8; p++) pw[p] = pk2(V[2 * p], V[2 * p + 1]);
    u32 s0 = hb ? pw[0] : pw[2];
    u32 s1 = hb ? pw[1] : pw[3];
    u32 s2 = hb ? pw[4] : pw[6];
    u32 s3 = hb ? pw[5] : pw[7];
    u32 r0 = bpermu(addr32, s0), r1 = bpermu(addr32, s1);
    u32 r2 = bpermu(addr32, s2), r3 = bpermu(addr32, s3);
    o[0] = hb ? r0 : pw[0]; o[1] = hb ? r1 : pw[1];
    o[2] = hb ? pw[2] : r0; o[3] = hb ? pw[3] : r1;
    o[4] = hb ? r2 : pw[4]; o[5] = hb ? r3 : pw[5];
    o[6] = hb ? pw[6] : r2; o[7] = hb ? pw[7] : r3;
}

// ---------- prep: fused gates -> W,V frags (+ Srow signs) in d_ws ----------
// frag f = l*8 + mat*4 + part*2 + kh; element frag[(f*64+lane)*8+j]; f=32,33: Srow.
// Layers 0..2: output index Gray-permuted (folds the separable part of the CNOT perm).
// Launch <<<2,1024>>> (2048-thread index space).
__global__ void tq_prep(const float* __restrict__ theta, uint16_t* __restrict__ frag) {
    __shared__ float g[NL * NQ][8];
    int tt = threadIdx.x;
    if (tt < NL * NQ) {
        float hx = 0.5f * theta[tt * 3 + 0];
        float hy = 0.5f * theta[tt * 3 + 1];
        float hz = 0.5f * theta[tt * 3 + 2];
        float cx = cosf(hx), sx = sinf(hx);
        float cy = cosf(hy), sy = sinf(hy);
        float cz = cosf(hz), sz = sinf(hz);
        float m00r = cx * cy, m00i = -sx * sy;
        float m01r = -cx * sy, m01i = -sx * cy;
        float m10r = cx * sy, m10i = -sx * cy;
        float m11r = cx * cy, m11i = sx * sy;
        float g00r, g00i, g01r, g01i, g10r, g10i, g11r, g11i;
        cmulh(m00r, m00i, cz, -sz, g00r, g00i);
        cmulh(m10r, m10i, cz, -sz, g10r, g10i);
        cmulh(m01r, m01i, cz, sz, g01r, g01i);
        cmulh(m11r, m11i, cz, sz, g11r, g11i);
        g[tt][0] = g00r; g[tt][1] = g00i; g[tt][2] = g01r; g[tt][3] = g01i;
        g[tt][4] = g10r; g[tt][5] = g10i; g[tt][6] = g11r; g[tt][7] = g11i;
    }
    __syncthreads();
    int t = blockIdx.x * blockDim.x + tt;  // 0..2047
    int lane = t & 63, kh = (t >> 6) & 1, part = (t >> 7) & 1, mat = (t >> 8) & 1, l = t >> 9;
    int mn = lane & 31, hf = (lane >> 5) & 1;
    int mne = (l < NL - 1) ? ((mn ^ (mn >> 1)) & 31) : mn;  // Gray fold for layers 0..2
#pragma unroll
    for (int j = 0; j < 8; j++) {
        int k = kh * 16 + hf * 8 + j;
        float pr = 1.f, pi = 0.f;
#pragma unroll
        for (int u = 0; u < 5; u++) {
            int q = mat ? (5 + u) : u;
            int bi_ = (k >> (4 - u)) & 1;
            int bo_ = (mne >> (4 - u)) & 1;
            const float* gg = g[l * NQ + q];
            float er = gg[(bi_ * 2 + bo_) * 2 + 0];
            float ei = gg[(bi_ * 2 + bo_) * 2 + 1];
            float nr, ni;
            cmulh(pr, pi, er, ei, nr, ni);
            pr = nr;
            pi = ni;
        }
        float v = part ? pi : pr;
        _Float16 h = (_Float16)v;
        frag[t * 8 + j] = __builtin_bit_cast(unsigned short, h);
    }
    // Srow sign frags (f=32,33): A[m][k] = (-1)^par(k & Mrow(m)), m = lane&31
    if (blockIdx.x == 0 && tt < 128) {
        int ln = tt & 63, kh2 = tt >> 6;
        int q = ln & 31, hf2 = (ln >> 5) & 1;
        u32 M = (q == 0) ? 0xFu : (q == 1) ? 0x18u : (q == 2) ? 0x1Cu : (q == 3) ? 0x1Eu : 0x1Fu;
        uint16_t* o = frag + ((32 + kh2) * 64 + ln) * 8;
#pragma unroll
        for (int j = 0; j < 8; j++) {
            int k = kh2 * 16 + hf2 * 8 + j;
            float v = (__builtin_popcount((u32)k & M) & 1) ? -1.f : 1.f;
            _Float16 h = (_Float16)v;
            o[j] = __builtin_bit_cast(unsigned short, h);
        }
    }
}

// ---------- main: one wave per sample; zero LDS allocation ----------
__global__ __launch_bounds__(256) void tq_main(
    const float* __restrict__ x, const float* __restrict__ encW,
    const float* __restrict__ encb, const uint16_t* __restrict__ frag,
    float* __restrict__ out, int batch) {
    int tid = threadIdx.x;
    int wave = (blockIdx.x * blockDim.x + tid) >> 6;
    int lane = tid & 63;
    if (wave >= batch) return;
    const int col = lane & 31;
    const int half_ = lane >> 5;
    const bool hb = half_ != 0;
    const bool c0 = (lane & 1) != 0;
    const int addr32 = (lane ^ 32) << 2;

    // ---- encoding: RY(enc) product state, built directly as A-frag ----
    float x0 = x[wave * 3 + 0], x1 = x[wave * 3 + 1], x2 = x[wave * 3 + 2];
    float hc = 1.f, hs = 0.f;
    if (lane < NQ) {
        float tta = 3.14159265358979323846f *
                    tanhf(x0 * encW[lane * 3 + 0] + x1 * encW[lane * 3 + 1] +
                          x2 * encW[lane * 3 + 2] + encb[lane]);
        float h = 0.5f * tta;
        hc = cosf(h);
        hs = sinf(h);
    }
    float fcv[NQ], fsv[NQ];
#pragma unroll
    for (int q = 0; q < NQ; q++) {
        fcv[q] = __shfl(hc, q, 64);
        fsv[q] = __shfl(hs, q, 64);
    }
    float colf = 1.f;
    colf *= ((col >> 4) & 1) ? -fsv[5] : fcv[5];
    colf *= ((col >> 3) & 1) ? -fsv[6] : fcv[6];
    colf *= ((col >> 2) & 1) ? -fsv[7] : fcv[7];
    colf *= ((col >> 1) & 1) ? -fsv[8] : fcv[8];
    colf *= (col & 1) ? -fsv[9] : fcv[9];
    float f1h = half_ ? -fsv[1] : fcv[1];
    float gj[8];
#pragma unroll
    for (int j = 0; j < 8; j++) {
        gj[j] = ((j & 4) ? -fsv[2] : fcv[2]) * ((j & 2) ? -fsv[3] : fcv[3]) *
                ((j & 1) ? -fsv[4] : fcv[4]);
    }
    f16x8 Sr0, Sr1, Si0, Si1;
#pragma unroll
    for (int j = 0; j < 8; j++) {
        Sr0[j] = (_Float16)(fcv[0] * f1h * gj[j] * colf);
        Sr1[j] = (_Float16)(-fsv[0] * f1h * gj[j] * colf);
        Si0[j] = (_Float16)0.f;
        Si1[j] = (_Float16)0.f;
    }

    const f16x8* fr = (const f16x8*)frag;
#define FRAG(f) fr[((f)*64) + lane]

    f32x16 Ur, Ui;
#pragma unroll
    for (int l = 0; l < NL; l++) {
        f16x8 Wr0 = FRAG(8 * l + 0), Wr1 = FRAG(8 * l + 1);
        f16x8 Wi0 = FRAG(8 * l + 2), Wi1 = FRAG(8 * l + 3);
        f16x8 Vr0 = FRAG(8 * l + 4), Vr1 = FRAG(8 * l + 5);
        f16x8 Vi0 = FRAG(8 * l + 6), Vi1 = FRAG(8 * l + 7);

        // GEMM1': T' = S^T * W^T = T^T (S-frag as A; W-frag as B)
        f32x16 Tr = zero16(), Ti = zero16();
        Tr = mfma16(Sr0, Wr0, Tr);
        Tr = mfma16(Sr1, Wr1, Tr);
        Ti = mfma16(Sr0, Wi0, Ti);
        Ti = mfma16(Sr1, Wi1, Ti);
        if (l > 0) {
            f16x8 nSi0 = negf(Si0), nSi1 = negf(Si1);
            Tr = mfma16(nSi0, Wi0, Tr);
            Tr = mfma16(nSi1, Wi1, Tr);
            Ti = mfma16(Si0, Wr0, Ti);
            Ti = mfma16(Si1, Wr1, Ti);
        }

        // C(T') -> A-frag(T): register half-exchange, no LDS
        u32 oR[8], oI[8];
        c2a(Tr, hb, addr32, oR);
        c2a(Ti, hb, addr32, oI);
        f16x8 TAr0 = mk8(oR[0], oR[1], oR[2], oR[3]);
        f16x8 TAr1 = mk8(oR[4], oR[5], oR[6], oR[7]);
        f16x8 TAi0 = mk8(oI[0], oI[1], oI[2], oI[3]);
        f16x8 TAi1 = mk8(oI[4], oI[5], oI[6], oI[7]);

        // GEMM2: U = T * V
        Ur = zero16();
        Ui = zero16();
        Ur = mfma16(TAr0, Vr0, Ur);
        Ur = mfma16(TAr1, Vr1, Ur);
        {
            f16x8 nTAi0 = negf(TAi0), nTAi1 = negf(TAi1);
            Ur = mfma16(nTAi0, Vi0, Ur);
            Ur = mfma16(nTAi1, Vi1, Ur);
        }
        Ui = mfma16(TAr0, Vi0, Ui);
        Ui = mfma16(TAr1, Vi1, Ui);
        Ui = mfma16(TAi0, Vr0, Ui);
        Ui = mfma16(TAi1, Vr1, Ui);

        if (l < NL - 1) {
            // X-step (residual CNOT perm; Gray part folded into prep).
            // Dataflow identical to R10 (correctness-proven), restructured into
            // per-t chunks to cap register liveness (R10's regression = RA spill).
            u32 srw0[4], srw1[4], siw0[4], siw1[4];
#pragma unroll
            for (int pp = 0; pp < 2; pp++) {
                u32 ka0, ka1, ka4, ka5, kb0, kb1, kb4, kb5;
#pragma unroll
                for (int u = 0; u < 2; u++) {
                    const int t = pp * 2 + u;
                    u32 wa = pk2(Ur[t], Ui[t]);
                    u32 wb = pk2(Ur[4 + t], Ui[4 + t]);
                    u32 wc = pk2(Ur[8 + t], Ui[8 + t]);
                    u32 wd = pk2(Ur[12 + t], Ui[12 + t]);
                    u32 xa, xb, xc, xd;
                    if ((t & 1) == 0) {
                        xa = c0 ? wc : wa;
                        xb = c0 ? wd : wb;
                        xc = c0 ? wa : wc;
                        xd = c0 ? wb : wd;
                    } else {
                        xa = swzu<0x1F>(c0 ? wa : wc);
                        xb = swzu<0x1F>(c0 ? wb : wd);
                        xc = swzu<0x1F>(c0 ? wc : wa);
                        xd = swzu<0x1F>(c0 ? wd : wb);
                    }
                    u32 ra = bpermu(addr32, hb ? xa : xb);
                    u32 rb2 = bpermu(addr32, hb ? xc : xd);
                    u32 v0 = hb ? ra : xa;   // glob k0[t]
                    u32 v4 = hb ? xb : ra;   // glob k0[4+t]
                    u32 w0 = hb ? rb2 : xc;  // glob k1[t]
                    u32 w4 = hb ? xd : rb2;  // glob k1[4+t]
                    if (u == 0) { ka0 = v0; ka4 = v4; kb0 = w0; kb4 = w4; }
                    else        { ka1 = v0; ka5 = v4; kb1 = w0; kb5 = w4; }
                }
                srw0[pp] = permlo(ka0, ka1); srw0[2 + pp] = permlo(ka4, ka5);
                srw1[pp] = permlo(kb0, kb1); srw1[2 + pp] = permlo(kb4, kb5);
                siw0[pp] = permhi(ka0, ka1); siw0[2 + pp] = permhi(ka4, ka5);
                siw1[pp] = permhi(kb0, kb1); siw1[2 + pp] = permhi(kb4, kb5);
            }
            Sr0 = mk8(srw0[0], srw0[1], srw0[2], srw0[3]);
            Sr1 = mk8(srw1[0], srw1[1], srw1[2], srw1[3]);
            Si0 = mk8(siw0[0], siw0[1], siw0[2], siw0[3]);
            Si1 = mk8(siw1[0], siw1[1], siw1[2], siw1[3]);
        }
    }

    // ---- epilogue: D = Srow * P (MFMA), Srow frags from d_ws ----
    f32x16 P;
#pragma unroll
    for (int gi = 0; gi < 16; gi++) P[gi] = Ur[gi] * Ur[gi] + Ui[gi] * Ui[gi];
    u32 po[8];
    c2a(P, hb, addr32, po);
    f16x8 PB0 = mk8(po[0], po[1], po[2], po[3]);
    f16x8 PB1 = mk8(po[4], po[5], po[6], po[7]);
    f16x8 Srw0 = FRAG(32), Srw1 = FRAG(33);
    f32x16 D = mfma16(Srw0, PB0, mfma16(Srw1, PB1, zero16()));

    u32 b4 = (col >> 4) & 1, b3 = (col >> 3) & 1, b2 = (col >> 2) & 1,
        b1 = (col >> 1) & 1, b0 = col & 1;
    u32 p4 = b4, p43 = p4 ^ b3, p432 = p43 ^ b2, p4321 = p432 ^ b1, pall = p4321 ^ b0;
    // slots 0..5: h=0 -> q {0,1,2,3,8,9}; h=1 -> q {4,5,6,7,-,-}
    u32 sg[6];
    sg[0] = hb ? 0u : pall;
    sg[1] = hb ? p4 : 0u;
    sg[2] = hb ? p43 : 0u;
    sg[3] = hb ? p432 : 0u;
    sg[4] = hb ? 0u : p4321;
    sg[5] = hb ? 0u : pall;
    float red[6];
#pragma unroll
    for (int s = 0; s < 6; s++) {
        float v = __uint_as_float(__float_as_uint(D[s]) ^ (sg[s] << 31));
        v += swz<1>(v);
        v += swz<2>(v);
        v += swz<4>(v);
        v += swz<8>(v);
        v += swz<16>(v);
        red[s] = v;
    }
    int cc = col - ((col >= 4) ? 4 : 0);
    float v = red[0];
    v = (cc == 1) ? red[1] : v;
    v = (cc == 2) ? red[2] : v;
    v = (cc == 3) ? red[3] : v;
    v = (cc == 4) ? red[4] : v;
    v = (cc == 5) ? red[5] : v;
    bool st = hb ? (col >= 4 && col < 8) : (col < 4 || col == 8 || col == 9);
    if (st) out[wave * NQ + col] = v;
}

extern "C" void kernel_launch(void* const* d_in, const int* in_sizes, int n_in,
                              void* d_out, int out_size, void* d_ws, size_t ws_size,
                              hipStream_t stream) {
    const float* x = (const float*)d_in[0];
    const float* encW = (const float*)d_in[1];
    const float* encb = (const float*)d_in[2];
    const float* th = (const float*)d_in[3];
    float* out = (float*)d_out;
    uint16_t* frag = (uint16_t*)d_ws;  // 34 frags * 64 lanes * 8 f16 (~35 KB)
    int batch = in_sizes[0] / 3;

    tq_prep<<<2, 1024, 0, stream>>>(th, frag);
    int total_threads = batch * 64;
    tq_main<<<(total_threads + 255) / 256, 256, 0, stream>>>(x, encW, encb, frag, out, batch);
}

// Round 13
// 98.087 us; speedup vs baseline: 1.4739x; 1.0420x over previous
//
#include <hip/hip_runtime.h>
#include <stdint.h>

#define NQ 10
#define NL 4

typedef unsigned int u32;
typedef _Float16 f16x8 __attribute__((ext_vector_type(8)));
typedef float f32x16 __attribute__((ext_vector_type(16)));
typedef u32 u32x4 __attribute__((ext_vector_type(4)));

// CNOT-ring permutation F = X ∘ (Gray⊗Gray), gather convention (R10/R11-validated):
// Gray folded into prep; runtime X: row ^= C0*16, col ^= R0*31, in registers.
//
// sigma slot-order (R12): every MFMA operand fragment uses slot->k map
// sigma(s): k = kh*16 + j2*8 + hf*4 + j1j0 (swap of hf/j2 vs standard). Then a
// C-layout output value gi lands at A-frag slot (kh=gi>>3, j=gi&7) in the SAME
// lane, so layout conversion = 16 pk2 only.
//
// X-step under sigma (R12 bugfix): dest slot j even (R0=0): in-lane, word
// select by own c0 (xe0 for kh0, xe1 for kh1, xe1 = inverse select of xe0).
// Dest slot j odd (R0=1): comes from lane C^31 whose c0 is negated -> the word
// a lane SENDS for kh0-odd slots is xe1, and for kh1-odd slots is xe0.
// (R12's failure: used xe0/xe1 for their own kh's odd path -> row-bit4 flip.)
//
// F^-1 sign masks (epilogue): bit_{9-q}(F^-1(r,c)) = par(r&Mrow_q)^par(c&Mcol_q)
// Mrow: q0=0x0F q1=0x18 q2=0x1C q3=0x1E q>=4=0x1F

// ---------- helpers ----------
__device__ __forceinline__ f32x16 mfma16(f16x8 a, f16x8 b, f32x16 c) {
    return __builtin_amdgcn_mfma_f32_32x32x16_f16(a, b, c, 0, 0, 0);
}
__device__ __forceinline__ f32x16 zero16() {
    f32x16 z;
#pragma unroll
    for (int i = 0; i < 16; i++) z[i] = 0.f;
    return z;
}
__device__ __forceinline__ f16x8 negf(f16x8 v) {
    u32x4 u = __builtin_bit_cast(u32x4, v);
#pragma unroll
    for (int i = 0; i < 4; i++) u[i] ^= 0x80008000u;
    return __builtin_bit_cast(f16x8, u);
}
__device__ __forceinline__ u32 pk2(float a, float b) {
    auto h = __builtin_amdgcn_cvt_pkrtz(a, b);
    return __builtin_bit_cast(u32, h);
}
// result = lo16(x) | hi16(s)<<16
__device__ __forceinline__ u32 mixhl(u32 s, u32 x) {
    return __builtin_amdgcn_perm(s, x, 0x07060100u);
}
__device__ __forceinline__ f16x8 mk8(u32 a, u32 b, u32 c, u32 d) {
    u32x4 v; v[0] = a; v[1] = b; v[2] = c; v[3] = d;
    return __builtin_bit_cast(f16x8, v);
}
template <int MASK>
__device__ __forceinline__ float swz(float v) {
    return __int_as_float(__builtin_amdgcn_ds_swizzle(__float_as_int(v), (MASK << 10) | 0x1F));
}
template <int MASK>
__device__ __forceinline__ u32 swzu(u32 v) {
    return (u32)__builtin_amdgcn_ds_swizzle((int)v, (MASK << 10) | 0x1F);
}
__device__ __forceinline__ void cmulh(float ar, float ai, float br, float bi, float& cr, float& ci) {
    cr = ar * br - ai * bi;
    ci = ar * bi + ai * br;
}

// ---------- prep: fused gates -> W,V frags (+ Srow signs) in d_ws ----------
// frag f = l*8 + mat*4 + part*2 + kh; element frag[(f*64+lane)*8+j]; f=32,33: Srow.
// k index uses sigma(slot): k = kh*16 + (j>>2)*8 + hf*4 + (j&3).
// Layers 0..2: output index Gray-permuted (separable part of CNOT perm).
// Launch <<<2,1024>>> (2048-thread index space).
__global__ void tq_prep(const float* __restrict__ theta, uint16_t* __restrict__ frag) {
    __shared__ float g[NL * NQ][8];
    int tt = threadIdx.x;
    if (tt < NL * NQ) {
        float hx = 0.5f * theta[tt * 3 + 0];
        float hy = 0.5f * theta[tt * 3 + 1];
        float hz = 0.5f * theta[tt * 3 + 2];
        float cx = cosf(hx), sx = sinf(hx);
        float cy = cosf(hy), sy = sinf(hy);
        float cz = cosf(hz), sz = sinf(hz);
        float m00r = cx * cy, m00i = -sx * sy;
        float m01r = -cx * sy, m01i = -sx * cy;
        float m10r = cx * sy, m10i = -sx * cy;
        float m11r = cx * cy, m11i = sx * sy;
        float g00r, g00i, g01r, g01i, g10r, g10i, g11r, g11i;
        cmulh(m00r, m00i, cz, -sz, g00r, g00i);
        cmulh(m10r, m10i, cz, -sz, g10r, g10i);
        cmulh(m01r, m01i, cz, sz, g01r, g01i);
        cmulh(m11r, m11i, cz, sz, g11r, g11i);
        g[tt][0] = g00r; g[tt][1] = g00i; g[tt][2] = g01r; g[tt][3] = g01i;
        g[tt][4] = g10r; g[tt][5] = g10i; g[tt][6] = g11r; g[tt][7] = g11i;
    }
    __syncthreads();
    int t = blockIdx.x * blockDim.x + tt;  // 0..2047
    int lane = t & 63, kh = (t >> 6) & 1, part = (t >> 7) & 1, mat = (t >> 8) & 1, l = t >> 9;
    int mn = lane & 31, hf = (lane >> 5) & 1;
    int mne = (l < NL - 1) ? ((mn ^ (mn >> 1)) & 31) : mn;  // Gray fold for layers 0..2
#pragma unroll
    for (int j = 0; j < 8; j++) {
        int k = kh * 16 + ((j >> 2)) * 8 + hf * 4 + (j & 3);  // sigma(slot)
        float pr = 1.f, pi = 0.f;
#pragma unroll
        for (int u = 0; u < 5; u++) {
            int q = mat ? (5 + u) : u;
            int bi_ = (k >> (4 - u)) & 1;
            int bo_ = (mne >> (4 - u)) & 1;
            const float* gg = g[l * NQ + q];
            float er = gg[(bi_ * 2 + bo_) * 2 + 0];
            float ei = gg[(bi_ * 2 + bo_) * 2 + 1];
            float nr, ni;
            cmulh(pr, pi, er, ei, nr, ni);
            pr = nr;
            pi = ni;
        }
        float v = part ? pi : pr;
        _Float16 h = (_Float16)v;
        frag[t * 8 + j] = __builtin_bit_cast(unsigned short, h);
    }
    // Srow sign frags (f=32,33): element(lane q, slot s) = (-1)^par(sigma(s) & Mrow(q))
    if (blockIdx.x == 0 && tt < 128) {
        int ln = tt & 63, kh2 = tt >> 6;
        int q = ln & 31, hf2 = (ln >> 5) & 1;
        u32 M = (q == 0) ? 0xFu : (q == 1) ? 0x18u : (q == 2) ? 0x1Cu : (q == 3) ? 0x1Eu : 0x1Fu;
        uint16_t* o = frag + ((32 + kh2) * 64 + ln) * 8;
#pragma unroll
        for (int j = 0; j < 8; j++) {
            int k = kh2 * 16 + ((j >> 2)) * 8 + hf2 * 4 + (j & 3);  // sigma(slot)
            float v = (__builtin_popcount((u32)k & M) & 1) ? -1.f : 1.f;
            _Float16 h = (_Float16)v;
            o[j] = __builtin_bit_cast(unsigned short, h);
        }
    }
}

// ---------- main: one wave per sample; zero LDS allocation ----------
__global__ __launch_bounds__(256) void tq_main(
    const float* __restrict__ x, const float* __restrict__ encW,
    const float* __restrict__ encb, const uint16_t* __restrict__ frag,
    float* __restrict__ out, int batch) {
    int tid = threadIdx.x;
    int wave = (blockIdx.x * blockDim.x + tid) >> 6;
    int lane = tid & 63;
    if (wave >= batch) return;
    const int col = lane & 31;
    const int half_ = lane >> 5;
    const bool hb = half_ != 0;
    const bool c0 = (lane & 1) != 0;

    // ---- encoding: RY(enc) product state, built directly as sigma-slot A-frag ----
    float x0 = x[wave * 3 + 0], x1 = x[wave * 3 + 1], x2 = x[wave * 3 + 2];
    float hc = 1.f, hs = 0.f;
    if (lane < NQ) {
        float tta = 3.14159265358979323846f *
                    tanhf(x0 * encW[lane * 3 + 0] + x1 * encW[lane * 3 + 1] +
                          x2 * encW[lane * 3 + 2] + encb[lane]);
        float h = 0.5f * tta;
        hc = cosf(h);
        hs = sinf(h);
    }
    float fcv[NQ], fsv[NQ];
#pragma unroll
    for (int q = 0; q < NQ; q++) {
        fcv[q] = __shfl(hc, q, 64);
        fsv[q] = __shfl(hs, q, 64);
    }
    float colf = 1.f;
    colf *= ((col >> 4) & 1) ? -fsv[5] : fcv[5];
    colf *= ((col >> 3) & 1) ? -fsv[6] : fcv[6];
    colf *= ((col >> 2) & 1) ? -fsv[7] : fcv[7];
    colf *= ((col >> 1) & 1) ? -fsv[8] : fcv[8];
    colf *= (col & 1) ? -fsv[9] : fcv[9];
    // row r = sigma(slot): q0<-kh, q1<-j2, q2<-hf, q3<-j1, q4<-j0
    float f2h = half_ ? -fsv[2] : fcv[2];
    float gj[8];
#pragma unroll
    for (int j = 0; j < 8; j++) {
        gj[j] = ((j & 4) ? -fsv[1] : fcv[1]) * ((j & 2) ? -fsv[3] : fcv[3]) *
                ((j & 1) ? -fsv[4] : fcv[4]);
    }
    f16x8 Sr0, Sr1, Si0, Si1;
#pragma unroll
    for (int j = 0; j < 8; j++) {
        Sr0[j] = (_Float16)(fcv[0] * f2h * gj[j] * colf);
        Sr1[j] = (_Float16)(-fsv[0] * f2h * gj[j] * colf);
        Si0[j] = (_Float16)0.f;
        Si1[j] = (_Float16)0.f;
    }

    const f16x8* fr = (const f16x8*)frag;
#define FRAG(f) fr[((f)*64) + lane]

    f32x16 Ur, Ui;
#pragma unroll
    for (int l = 0; l < NL; l++) {
        f16x8 Wr0 = FRAG(8 * l + 0), Wr1 = FRAG(8 * l + 1);
        f16x8 Wi0 = FRAG(8 * l + 2), Wi1 = FRAG(8 * l + 3);
        f16x8 Vr0 = FRAG(8 * l + 4), Vr1 = FRAG(8 * l + 5);
        f16x8 Vi0 = FRAG(8 * l + 6), Vi1 = FRAG(8 * l + 7);

        // GEMM1': T' = S^T * W^T = T^T (S-frag as A; W-frag as B; both sigma-ordered)
        f32x16 Tr = zero16(), Ti = zero16();
        Tr = mfma16(Sr0, Wr0, Tr);
        Tr = mfma16(Sr1, Wr1, Tr);
        Ti = mfma16(Sr0, Wi0, Ti);
        Ti = mfma16(Sr1, Wi1, Ti);
        if (l > 0) {
            f16x8 nSi0 = negf(Si0), nSi1 = negf(Si1);
            Tr = mfma16(nSi0, Wi0, Tr);
            Tr = mfma16(nSi1, Wi1, Tr);
            Ti = mfma16(Si0, Wr0, Ti);
            Ti = mfma16(Si1, Wr1, Ti);
        }

        // C(T') -> sigma-slot A-frag(T): pure pack, same lane (no DS, no selects)
        f16x8 TAr0, TAr1, TAi0, TAi1;
        {
            u32 a0[4], a1[4], b0[4], b1[4];
#pragma unroll
            for (int p = 0; p < 4; p++) {
                a0[p] = pk2(Tr[2 * p], Tr[2 * p + 1]);
                a1[p] = pk2(Tr[8 + 2 * p], Tr[8 + 2 * p + 1]);
                b0[p] = pk2(Ti[2 * p], Ti[2 * p + 1]);
                b1[p] = pk2(Ti[8 + 2 * p], Ti[8 + 2 * p + 1]);
            }
            TAr0 = mk8(a0[0], a0[1], a0[2], a0[3]);
            TAr1 = mk8(a1[0], a1[1], a1[2], a1[3]);
            TAi0 = mk8(b0[0], b0[1], b0[2], b0[3]);
            TAi1 = mk8(b1[0], b1[1], b1[2], b1[3]);
        }

        // GEMM2: U = T * V
        Ur = zero16();
        Ui = zero16();
        Ur = mfma16(TAr0, Vr0, Ur);
        Ur = mfma16(TAr1, Vr1, Ur);
        {
            f16x8 nTAi0 = negf(TAi0), nTAi1 = negf(TAi1);
            Ur = mfma16(nTAi0, Vi0, Ur);
            Ur = mfma16(nTAi1, Vi1, Ur);
        }
        Ui = mfma16(TAr0, Vi0, Ui);
        Ui = mfma16(TAr1, Vi1, Ui);
        Ui = mfma16(TAi0, Vr0, Ui);
        Ui = mfma16(TAi1, Vr1, Ui);

        if (l < NL - 1) {
            // X-step + sigma A-frag assembly (in-lane; R12 select-inversion FIXED):
            // word wr0[p]/wr1[p] = rows gi=(2p,2p+1) of kh-group 0/1.
            // even slots (R0=0, in-lane):  kh0 <- xe0 = c0?wr1:wr0, kh1 <- xe1 = c0?wr0:wr1
            // odd  slots (R0=1, via ^31): dest c0 is negated -> kh0 hi16 <- swz(xe1),
            //                                                     kh1 hi16 <- swz(xe0)
            u32 wr0[4], wr1[4], wi0[4], wi1[4];
#pragma unroll
            for (int p = 0; p < 4; p++) {
                wr0[p] = pk2(Ur[2 * p], Ur[2 * p + 1]);
                wr1[p] = pk2(Ur[8 + 2 * p], Ur[8 + 2 * p + 1]);
                wi0[p] = pk2(Ui[2 * p], Ui[2 * p + 1]);
                wi1[p] = pk2(Ui[8 + 2 * p], Ui[8 + 2 * p + 1]);
            }
            u32 s0[4], s1[4], t0[4], t1[4];
#pragma unroll
            for (int p = 0; p < 4; p++) {
                u32 xe0r = c0 ? wr1[p] : wr0[p];
                u32 xe1r = c0 ? wr0[p] : wr1[p];
                u32 xe0i = c0 ? wi1[p] : wi0[p];
                u32 xe1i = c0 ? wi0[p] : wi1[p];
                s0[p] = mixhl(swzu<0x1F>(xe1r), xe0r);
                s1[p] = mixhl(swzu<0x1F>(xe0r), xe1r);
                t0[p] = mixhl(swzu<0x1F>(xe1i), xe0i);
                t1[p] = mixhl(swzu<0x1F>(xe0i), xe1i);
            }
            Sr0 = mk8(s0[0], s0[1], s0[2], s0[3]);
            Sr1 = mk8(s1[0], s1[1], s1[2], s1[3]);
            Si0 = mk8(t0[0], t0[1], t0[2], t0[3]);
            Si1 = mk8(t1[0], t1[1], t1[2], t1[3]);
        }
    }

    // ---- epilogue: D = Srow * P (MFMA); P packed as sigma-slot B-frag in-lane ----
    f32x16 P;
#pragma unroll
    for (int gi = 0; gi < 16; gi++) P[gi] = Ur[gi] * Ur[gi] + Ui[gi] * Ui[gi];
    f16x8 PB0, PB1;
    {
        u32 p0[4], p1[4];
#pragma unroll
        for (int p = 0; p < 4; p++) {
            p0[p] = pk2(P[2 * p], P[2 * p + 1]);
            p1[p] = pk2(P[8 + 2 * p], P[8 + 2 * p + 1]);
        }
        PB0 = mk8(p0[0], p0[1], p0[2], p0[3]);
        PB1 = mk8(p1[0], p1[1], p1[2], p1[3]);
    }
    f16x8 Srw0 = FRAG(32), Srw1 = FRAG(33);
    f32x16 D = mfma16(Srw0, PB0, mfma16(Srw1, PB1, zero16()));

    u32 b4 = (col >> 4) & 1, b3 = (col >> 3) & 1, b2 = (col >> 2) & 1,
        b1 = (col >> 1) & 1, b0 = col & 1;
    u32 p4 = b4, p43 = p4 ^ b3, p432 = p43 ^ b2, p4321 = p432 ^ b1, pall = p4321 ^ b0;
    // slots 0..5: h=0 -> q {0,1,2,3,8,9}; h=1 -> q {4,5,6,7,-,-}
    u32 sg[6];
    sg[0] = hb ? 0u : pall;
    sg[1] = hb ? p4 : 0u;
    sg[2] = hb ? p43 : 0u;
    sg[3] = hb ? p432 : 0u;
    sg[4] = hb ? 0u : p4321;
    sg[5] = hb ? 0u : pall;
    float red[6];
#pragma unroll
    for (int s = 0; s < 6; s++) {
        float v = __uint_as_float(__float_as_uint(D[s]) ^ (sg[s] << 31));
        v += swz<1>(v);
        v += swz<2>(v);
        v += swz<4>(v);
        v += swz<8>(v);
        v += swz<16>(v);
        red[s] = v;
    }
    int cc = col - ((col >= 4) ? 4 : 0);
    float v = red[0];
    v = (cc == 1) ? red[1] : v;
    v = (cc == 2) ? red[2] : v;
    v = (cc == 3) ? red[3] : v;
    v = (cc == 4) ? red[4] : v;
    v = (cc == 5) ? red[5] : v;
    bool st = hb ? (col >= 4 && col < 8) : (col < 4 || col == 8 || col == 9);
    if (st) out[wave * NQ + col] = v;
}

extern "C" void kernel_launch(void* const* d_in, const int* in_sizes, int n_in,
                              void* d_out, int out_size, void* d_ws, size_t ws_size,
                              hipStream_t stream) {
    const float* x = (const float*)d_in[0];
    const float* encW = (const float*)d_in[1];
    const float* encb = (const float*)d_in[2];
    const float* th = (const float*)d_in[3];
    float* out = (float*)d_out;
    uint16_t* frag = (uint16_t*)d_ws;  // 34 frags * 64 lanes * 8 f16 (~35 KB)
    int batch = in_sizes[0] / 3;

    tq_prep<<<2, 1024, 0, stream>>>(th, frag);
    int total_threads = batch * 64;
    tq_main<<<(total_threads + 255) / 256, 256, 0, stream>>>(x, encW, encb, frag, out, batch);
}